// Round 8
// baseline (256.176 us; speedup 1.0000x reference)
//
#include <hip/hip_runtime.h>

// Attention forward, (B,H,D,N)=(4,16,64,2048), fp32 in/out. Flash-style.
// Round 12: R9 base (91.5us, best) + T15 cross-tile pipeline. PV lags one
// tile: iteration kt issues QK(kt), then lac+PV(kt-1) from register pgP +
// LDS V(kt-1) (independent of QK), then exp2/pack(kt)->pgP. Breaks the
// QK->exp2->PV serial chain; exp2 overlaps prev-tile PV MFMAs. 3 rotating
// K/V buffers (55KB/block) keep V(kt-1) alive while tile kt+1 stages.
// Geometry/layout = R9: 256-q tile, 8 waves x 32 q-cols, 512 thr, grid 512.

#define DDIM 64
#define NSEQ 2048
#define STR  72               // f16 elems per LDS row (64 + 8 pad), 144 B
#define ROWB (STR * 2)
#define BUFB (128 * ROWB)     // one K+V buffer: 64 K-rows + 64 V-rows = 18432 B

typedef _Float16 half8   __attribute__((ext_vector_type(8)));
typedef _Float16 half4v  __attribute__((ext_vector_type(4)));
typedef _Float16 half2v  __attribute__((ext_vector_type(2)));
typedef float    float4v __attribute__((ext_vector_type(4)));

__global__ __launch_bounds__(512, 4) void attn_fwd(
    const float* __restrict__ qg, const float* __restrict__ kg,
    const float* __restrict__ vg, float* __restrict__ og) {
  // Three K/V buffers (18432 B each). tile kt lives in buffer (kt+1)%3.
  // Q (256 rows) pre-staged across buf0+buf1, consumed to regs first.
  __shared__ __align__(16) char smem[3 * BUFB];

  const int t    = threadIdx.x;
  const int lane = t & 63;
  const int w    = t >> 6;      // wave 0..7 -> query cols w*32 .. w*32+31
  const int n16  = lane & 15;
  const int quad = lane >> 4;

  // XCD swizzle: 64 blocks/XCD; same-XCD slots walk q-tiles of 8 heads.
  const int bid  = blockIdx.x;
  const int head = ((bid & 7) << 3) | (bid >> 6);
  const int tile = (bid >> 3) & 7;
  const int i0   = tile * 256;

  const float* qh = qg + (size_t)head * DDIM * NSEQ;
  const float* kh = kg + (size_t)head * DDIM * NSEQ;
  const float* vh = vg + (size_t)head * DDIM * NSEQ;

  // staging indices (512 threads)
  const int dp = t & 31;        // d-pair (K transpose staging)
  const int iq = t >> 5;        // 0..15, K j-chunk of 4
  const int vd = t >> 3;        // V row (d), 0..63
  const int sj = t & 7;         // V k-slot 0..7
  const int vg_ = sj >> 2;      // g of slot
  const int vq  = sj & 3;       // quad of slot

  const float* kp  = kh + (2 * dp) * NSEQ + iq * 4;
  const float* vpA = vh + vd * NSEQ + vg_ * 32 + vq * 4;  // first 4 cols of slot
  // second 4 cols of slot = vpA + 16

  // issue tile-0 global loads first: HBM latency hides under Q prestage
  float4v ka, kb, va, vb;
  ka = *(const float4v*)(kp);
  kb = *(const float4v*)(kp + NSEQ);
  va = *(const float4v*)(vpA);
  vb = *(const float4v*)(vpA + 16);

  // ---- pre-stage Q: q[d][i0+..] -> Qt[i][d] (256 rows, buf0+buf1) ----
  {
    _Float16* Qt = (_Float16*)smem;
    const float mul = 0.125f * 1.44269504088896340736f;
#pragma unroll
    for (int h = 0; h < 4; ++h) {
      const float* r0 = qh + (2 * dp) * NSEQ + i0 + h * 64 + iq * 4;
      float4v a = *(const float4v*)(r0);
      float4v b = *(const float4v*)(r0 + NSEQ);
      _Float16* base = Qt + (h * 64 + iq * 4) * STR + 2 * dp;
#pragma unroll
      for (int s = 0; s < 4; ++s) {
        half2v hh = {(_Float16)(a[s] * mul), (_Float16)(b[s] * mul)};
        *(half2v*)(base + s * STR) = hh;
      }
    }
  }
  __syncthreads();

  // Q B-fragments — live all kernel (2 x 16-col groups per wave)
  const _Float16* Qt = (const _Float16*)smem;
  half8 bq[2][2];
#pragma unroll
  for (int ig = 0; ig < 2; ++ig) {
    bq[ig][0] = *(const half8*)(Qt + (w * 32 + ig * 16 + n16) * STR + quad * 8);
    bq[ig][1] = *(const half8*)(Qt + (w * 32 + ig * 16 + n16) * STR + 32 + quad * 8);
  }
  __syncthreads();  // all Q reads drained before tile 0 overwrites buf1

  const half8 ones = {1.0f16, 1.0f16, 1.0f16, 1.0f16,
                      1.0f16, 1.0f16, 1.0f16, 1.0f16};

  float4v o[2][4];          // [ig][dt]: O^T[d = dt*16+quad*4+r][i-group ig]
  float4v lac[2];           // row-sum accumulators (all regs equal l[n16])
  half8  pgP[2][2];         // prev tile's P as K=32 B-operands (persists)
#pragma unroll
  for (int ig = 0; ig < 2; ++ig) {
#pragma unroll
    for (int dt = 0; dt < 4; ++dt) o[ig][dt] = (float4v){0.f, 0.f, 0.f, 0.f};
    lac[ig] = (float4v){0.f, 0.f, 0.f, 0.f};
    pgP[ig][0] = (half8){0,0,0,0,0,0,0,0};
    pgP[ig][1] = (half8){0,0,0,0,0,0,0,0};
  }

  // ---- stage tile 0 into buf1 ----
  {
    _Float16* Ktw = (_Float16*)(smem + BUFB);
    _Float16* base = Ktw + (iq * 4) * STR + 2 * dp;
#pragma unroll
    for (int s = 0; s < 4; ++s) {
      half2v hh = {(_Float16)ka[s], (_Float16)kb[s]};
      *(half2v*)(base + s * STR) = hh;
    }
    // V pre-permuted: slot sj holds orig cols {g*32+vq*4..+3, g*32+16+vq*4..+3}
    half8 hv = {(_Float16)va[0], (_Float16)va[1], (_Float16)va[2], (_Float16)va[3],
                (_Float16)vb[0], (_Float16)vb[1], (_Float16)vb[2], (_Float16)vb[3]};
    *(half8*)(Ktw + 64 * STR + vd * STR + sj * 8) = hv;
  }
  __syncthreads();

  // buffer rotation: bc = tile kt (K+V reads), bp = tile kt-1 (V for PV),
  // bw = tile kt+1 (staging writes). tile kt lives in buffer (kt+1)%3.
  int bc = 1, bp = 0, bw = 2;

  for (int kt = 0; kt < 32; ++kt) {
    const _Float16* Kt = (const _Float16*)(smem + bc * BUFB);

    // ---- prefetch next tile into regs (in flight during compute) ----
    if (kt < 31) {
      const int j1 = (kt + 1) * 64;
      ka = *(const float4v*)(kp + j1);
      kb = *(const float4v*)(kp + NSEQ + j1);
      va = *(const float4v*)(vpA + j1);
      vb = *(const float4v*)(vpA + j1 + 16);
    }

    // ---- S^T + exp2 per j16 block (K-frags reused across 2 i-groups) ----
    half4v p[2][4];  // [ig][jt]
#pragma unroll
    for (int jt = 0; jt < 4; ++jt) {
      half8 kfa = *(const half8*)(Kt + (jt * 16 + n16) * STR + quad * 8);
      half8 kfb = *(const half8*)(Kt + (jt * 16 + n16) * STR + 32 + quad * 8);
#pragma unroll
      for (int ig = 0; ig < 2; ++ig) {
        float4v sa = {0.f, 0.f, 0.f, 0.f};
        sa = __builtin_amdgcn_mfma_f32_16x16x32_f16(kfa, bq[ig][0], sa, 0, 0, 0);
        sa = __builtin_amdgcn_mfma_f32_16x16x32_f16(kfb, bq[ig][1], sa, 0, 0, 0);
        p[ig][jt] = (half4v){(_Float16)__builtin_amdgcn_exp2f(sa[0]),
                             (_Float16)__builtin_amdgcn_exp2f(sa[1]),
                             (_Float16)__builtin_amdgcn_exp2f(sa[2]),
                             (_Float16)__builtin_amdgcn_exp2f(sa[3])};
      }
    }

    // ---- PV + lac for tile kt-1 (indep of this tile's QK/exp2):
    //      pgP regs + V(kt-1) from buffer bp ----
    if (kt > 0) {
      const _Float16* Vp = (const _Float16*)(smem + bp * BUFB) + 64 * STR;
      __builtin_amdgcn_s_setprio(1);
#pragma unroll
      for (int ig = 0; ig < 2; ++ig) {
        lac[ig] = __builtin_amdgcn_mfma_f32_16x16x32_f16(ones, pgP[ig][0], lac[ig], 0, 0, 0);
        lac[ig] = __builtin_amdgcn_mfma_f32_16x16x32_f16(ones, pgP[ig][1], lac[ig], 0, 0, 0);
      }
#pragma unroll
      for (int dt = 0; dt < 4; ++dt) {
#pragma unroll
        for (int g = 0; g < 2; ++g) {
          half8 vaf = *(const half8*)(Vp + (dt * 16 + n16) * STR + (g * 4 + quad) * 8);
#pragma unroll
          for (int ig = 0; ig < 2; ++ig) {
            o[ig][dt] = __builtin_amdgcn_mfma_f32_16x16x32_f16(
                vaf, pgP[ig][g], o[ig][dt], 0, 0, 0);
          }
        }
      }
      __builtin_amdgcn_s_setprio(0);
    }

    // ---- pack this tile's P -> pgP (consumed next iteration) ----
#pragma unroll
    for (int ig = 0; ig < 2; ++ig) {
      pgP[ig][0] = __builtin_shufflevector(p[ig][0], p[ig][1], 0, 1, 2, 3, 4, 5, 6, 7);
      pgP[ig][1] = __builtin_shufflevector(p[ig][2], p[ig][3], 0, 1, 2, 3, 4, 5, 6, 7);
    }

    // ---- write prefetched tile kt+1 to buffer bw, single barrier ----
    if (kt < 31) {
      _Float16* Ktw = (_Float16*)(smem + bw * BUFB);
      _Float16* base = Ktw + (iq * 4) * STR + 2 * dp;
#pragma unroll
      for (int s = 0; s < 4; ++s) {
        half2v hh = {(_Float16)ka[s], (_Float16)kb[s]};
        *(half2v*)(base + s * STR) = hh;
      }
      half8 hv = {(_Float16)va[0], (_Float16)va[1], (_Float16)va[2], (_Float16)va[3],
                  (_Float16)vb[0], (_Float16)vb[1], (_Float16)vb[2], (_Float16)vb[3]};
      *(half8*)(Ktw + 64 * STR + vd * STR + sj * 8) = hv;
      __syncthreads();
    }

    // rotate buffers: bp <- bc, bc <- bw, bw <- old bp
    const int tmp = bp; bp = bc; bc = bw; bw = tmp;
  }

  // ---- drain: PV + lac for tile 31 (buffer bp after final rotation) ----
  {
    const _Float16* Vp = (const _Float16*)(smem + bp * BUFB) + 64 * STR;
    __builtin_amdgcn_s_setprio(1);
#pragma unroll
    for (int ig = 0; ig < 2; ++ig) {
      lac[ig] = __builtin_amdgcn_mfma_f32_16x16x32_f16(ones, pgP[ig][0], lac[ig], 0, 0, 0);
      lac[ig] = __builtin_amdgcn_mfma_f32_16x16x32_f16(ones, pgP[ig][1], lac[ig], 0, 0, 0);
    }
#pragma unroll
    for (int dt = 0; dt < 4; ++dt) {
#pragma unroll
      for (int g = 0; g < 2; ++g) {
        half8 vaf = *(const half8*)(Vp + (dt * 16 + n16) * STR + (g * 4 + quad) * 8);
#pragma unroll
        for (int ig = 0; ig < 2; ++ig) {
          o[ig][dt] = __builtin_amdgcn_mfma_f32_16x16x32_f16(
              vaf, pgP[ig][g], o[ig][dt], 0, 0, 0);
        }
      }
    }
    __builtin_amdgcn_s_setprio(0);
  }

  // ---- epilogue: all regs of lac hold l[i]; direct O^T stores ----
#pragma unroll
  for (int ig = 0; ig < 2; ++ig) {
    const float inv = 1.0f / lac[ig][0];
    float* ob = og + (size_t)head * DDIM * NSEQ + i0 + w * 32 + ig * 16 + n16;
#pragma unroll
    for (int dt = 0; dt < 4; ++dt) {
#pragma unroll
      for (int r = 0; r < 4; ++r) {
        ob[(size_t)(dt * 16 + quad * 4 + r) * NSEQ] = o[ig][dt][r] * inv;
      }
    }
  }
}

extern "C" void kernel_launch(void* const* d_in, const int* in_sizes, int n_in,
                              void* d_out, int out_size, void* d_ws, size_t ws_size,
                              hipStream_t stream) {
  (void)in_sizes; (void)n_in; (void)d_ws; (void)ws_size; (void)out_size;
  const float* q = (const float*)d_in[0];
  const float* k = (const float*)d_in[1];
  const float* v = (const float*)d_in[2];
  attn_fwd<<<dim3(512), dim3(512), 0, stream>>>(q, k, v, (float*)d_out);
}